// Round 1
// 365.834 us; speedup vs baseline: 1.0449x; 1.0449x over previous
//
#include <hip/hip_runtime.h>
#include <hip/hip_fp16.h>
#include <math.h>

// B=8, S=1024, D=256, H=8, DH=32
constexpr int Bsz = 8, Ssz = 1024, Dsz = 256, Hn = 8, DHn = 32;
constexpr int SST = 1160;  // attn LDS row stride in shorts

typedef __attribute__((ext_vector_type(8))) short short8;
typedef __attribute__((ext_vector_type(4))) float floatx4;

#define DEV static __device__ __forceinline__

DEV short f2bf(float f) {  // fp32 -> bf16 RNE
  union { float f; unsigned u; } x; x.f = f;
  return (short)((x.u + 0x7fffu + ((x.u >> 16) & 1u)) >> 16);
}
DEV short f2h(float f) {
  __half h = __float2half(f);
  return *(short*)&h;
}
DEV float wsum(float v) {
#pragma unroll
  for (int off = 32; off > 0; off >>= 1) v += __shfl_xor(v, off, 64);
  return v;
}
DEV float wscan_incl(float v) {
  float x = v;
  const int ln = threadIdx.x & 63;
#pragma unroll
  for (int off = 1; off < 64; off <<= 1) {
    float y = __shfl_up(x, off, 64);
    if (ln >= off) x += y;
  }
  return x;
}

// ============ W pre-convert: fp32 row-major -> bf16 MFMA B-frag order =======
// layout: [kblk(8)][ntile(16)][lane(64)][8 bf16]; element =
//   W[ntile*16 + (lane&15)][kblk*32 + (lane>>4)*8 + j]
__global__ __launch_bounds__(256) void cvt_wfrag(const float* __restrict__ Wq,
                                                 const float* __restrict__ Wv,
                                                 const float* __restrict__ Wo,
                                                 short* __restrict__ dst) {
  const int which = blockIdx.y;
  const float* W = (which == 0) ? Wq : (which == 1) ? Wv : Wo;
  const int t = blockIdx.x * 256 + threadIdx.x;  // 0..8191
  const int ln = t & 63, nt = (t >> 6) & 15, kblk = t >> 10;
  const float* src = W + (size_t)(nt * 16 + (ln & 15)) * 256 + kblk * 32 + (ln >> 4) * 8;
  const float4 a = *(const float4*)src;
  const float4 b = *(const float4*)(src + 4);
  const float tmp[8] = {a.x, a.y, a.z, a.w, b.x, b.y, b.z, b.w};
  short8 s;
#pragma unroll
  for (int j = 0; j < 8; ++j) s[j] = f2bf(tmp[j]);
  *(short8*)(dst + ((size_t)which << 16) + (size_t)t * 8) = s;
}

// ============ projections: 32 rows x full N=256 per block ==================
// Xs: 32x80 bf16, granule-XOR swizzled. Wave w owns n-range [w*64, w*64+64).
__global__ __launch_bounds__(256, 4) void proj_qkv2(
    const float* __restrict__ qi, const float* __restrict__ ki, const float* __restrict__ vi,
    const short* __restrict__ Wfrag, const float* __restrict__ bq, const float* __restrict__ bv,
    short* __restrict__ qh, short* __restrict__ kh, short* __restrict__ vt) {
  __shared__ short Xs[32 * 80];
  const int which = blockIdx.y;
  const float* X = (which == 0) ? qi : (which == 1) ? ki : vi;
  const short* Wf = Wfrag + ((which == 2) ? (1 << 16) : 0);
  const float* bias = (which == 2) ? bv : bq;
  const int tid = threadIdx.x, ln = tid & 63, w = tid >> 6;
  const int lm = ln & 15, qq = ln >> 4;
  const int bm = blockIdx.x;  // 256 blocks of 32 rows
  const float* Xb = X + (size_t)bm * 32 * 256;
  floatx4 acc[2][4] = {};

  for (int k0 = 0; k0 < 4; ++k0) {
    __syncthreads();
    {
      const int row = tid >> 3, cg = tid & 7;
#pragma unroll
      for (int i = 0; i < 2; ++i) {
        const float4 f = *(const float4*)(Xb + (size_t)row * 256 + k0 * 64 + cg * 8 + i * 4);
        short4 s; s.x = f2bf(f.x); s.y = f2bf(f.y); s.z = f2bf(f.z); s.w = f2bf(f.w);
        *(short4*)(Xs + row * 80 + (cg ^ (row & 7)) * 8 + i * 4) = s;
      }
    }
    __syncthreads();
#pragma unroll
    for (int ks = 0; ks < 2; ++ks) {
      const int kblk = k0 * 2 + ks;
      short8 a[2], b[4];
#pragma unroll
      for (int mt = 0; mt < 2; ++mt) {
        const int row = mt * 16 + lm;
        a[mt] = *(const short8*)(Xs + row * 80 + (((ks * 4 + qq)) ^ (row & 7)) * 8);
      }
#pragma unroll
      for (int nt = 0; nt < 4; ++nt)
        b[nt] = *(const short8*)(Wf + ((size_t)(kblk * 16 + w * 4 + nt) * 64 + ln) * 8);
#pragma unroll
      for (int mt = 0; mt < 2; ++mt)
#pragma unroll
        for (int nt = 0; nt < 4; ++nt)
          acc[mt][nt] = __builtin_amdgcn_mfma_f32_16x16x32_bf16(a[mt], b[nt], acc[mt][nt], 0, 0, 0);
    }
  }

#pragma unroll
  for (int mt = 0; mt < 2; ++mt) {
#pragma unroll
    for (int nt = 0; nt < 4; ++nt) {
      const int n = w * 64 + nt * 16 + lm;
      const float bval = bias[n];
      const int m0 = bm * 32 + mt * 16 + qq * 4;
      const int h = n >> 5, dh = n & 31;
      if (which <= 1) {  // head-split [B,H,S,DH]
        short* dst = (which == 0) ? qh : kh;
#pragma unroll
        for (int r = 0; r < 4; ++r) {
          const int m = m0 + r, b_ = m >> 10, s = m & 1023;
          dst[(((size_t)(b_ * Hn + h) << 10) + s) * DHn + dh] = f2bf(acc[mt][nt][r] + bval);
        }
      } else {  // V^T [B,H,DH,S]
        const int b_ = m0 >> 10, s0 = m0 & 1023;
        short4 pk;
        pk.x = f2bf(acc[mt][nt][0] + bval);
        pk.y = f2bf(acc[mt][nt][1] + bval);
        pk.z = f2bf(acc[mt][nt][2] + bval);
        pk.w = f2bf(acc[mt][nt][3] + bval);
        *(short4*)(vt + ((size_t)((b_ * Hn + h) * DHn + dh) << 10) + s0) = pk;
      }
    }
  }
}

__global__ __launch_bounds__(256, 4) void proj_out2(
    const short* __restrict__ oc, const short* __restrict__ Wfrag,
    const float* __restrict__ bo, float* __restrict__ out) {
  __shared__ short Xs[32 * 80];
  const short* Wf = Wfrag + (2 << 16);
  const int tid = threadIdx.x, ln = tid & 63, w = tid >> 6;
  const int lm = ln & 15, qq = ln >> 4;
  const int bm = blockIdx.x;
  const short* Xb = oc + (size_t)bm * 32 * 256;
  floatx4 acc[2][4] = {};

  for (int k0 = 0; k0 < 4; ++k0) {
    __syncthreads();
    {
      const int row = tid >> 3, cg = tid & 7;
      const short8 s = *(const short8*)(Xb + (size_t)row * 256 + k0 * 64 + cg * 8);
      *(short8*)(Xs + row * 80 + (cg ^ (row & 7)) * 8) = s;
    }
    __syncthreads();
#pragma unroll
    for (int ks = 0; ks < 2; ++ks) {
      const int kblk = k0 * 2 + ks;
      short8 a[2], b[4];
#pragma unroll
      for (int mt = 0; mt < 2; ++mt) {
        const int row = mt * 16 + lm;
        a[mt] = *(const short8*)(Xs + row * 80 + (((ks * 4 + qq)) ^ (row & 7)) * 8);
      }
#pragma unroll
      for (int nt = 0; nt < 4; ++nt)
        b[nt] = *(const short8*)(Wf + ((size_t)(kblk * 16 + w * 4 + nt) * 64 + ln) * 8);
#pragma unroll
      for (int mt = 0; mt < 2; ++mt)
#pragma unroll
        for (int nt = 0; nt < 4; ++nt)
          acc[mt][nt] = __builtin_amdgcn_mfma_f32_16x16x32_bf16(a[mt], b[nt], acc[mt][nt], 0, 0, 0);
    }
  }
#pragma unroll
  for (int mt = 0; mt < 2; ++mt)
#pragma unroll
    for (int nt = 0; nt < 4; ++nt) {
      const int n = w * 64 + nt * 16 + lm;
      const float bval = bo[n];
      const int m0 = bm * 32 + mt * 16 + qq * 4;
#pragma unroll
      for (int r = 0; r < 4; ++r)
        __builtin_nontemporal_store(acc[mt][nt][r] + bval, out + (size_t)(m0 + r) * 256 + n);
    }
}

// ======================= fused attention ===================================
// phase2 v2: no max-subtraction (scores are O(10), exp() safe in fp32 and
// identical after normalization), pass-4 exp fused into pass-3.  Removes two
// 6-shuffle dependent wave-max chains per row and one full pass per element.
template <int NP>
DEV void phase2(short* ss, float* shead, int row0, int w, int ln, float g) {
  const int c0 = ln * 4;
  for (int rr = 0; rr < 4; ++rr) {
    const int m = w * 4 + rr;
    const int irow = row0 + m;
    short* srow = ss + m * SST;

    float sv[NP * 4], e[NP * 4];

    // pass A: load raw fp16 scores, e = exp(s) (masked), row-wide exclusive
    // prefix state for the cumulative-distance term.
    float carry = 0.f, excl[NP];
#pragma unroll
    for (int p = 0; p < NP; ++p) {
      const uint2 u = *(const uint2*)(srow + p * 256 + c0);
      const float2 f0 = __half22float2(*(const __half2*)&u.x);
      const float2 f1 = __half22float2(*(const __half2*)&u.y);
      sv[p * 4 + 0] = f0.x; sv[p * 4 + 1] = f0.y;
      sv[p * 4 + 2] = f1.x; sv[p * 4 + 3] = f1.y;
      float ls = 0.f;
#pragma unroll
      for (int j = 0; j < 4; ++j) {
        const int c = p * 256 + c0 + j;
        e[p * 4 + j] = (c <= irow) ? __expf(sv[p * 4 + j]) : 0.f;
        ls += e[p * 4 + j];
      }
      const float incl = wscan_incl(ls);
      excl[p] = carry + incl - ls;
      carry += __shfl(incl, 63, 64);
    }
    const float Z = carry, invZ = 1.f / Z;

    // pass B: distance decay + second (unnormalized) softmax numerator.
    // eff = exp(g*dist) <= 1 since g <= 0, so the 1e5 upper clip never binds.
    float ls2 = 0.f;
#pragma unroll
    for (int p = 0; p < NP; ++p) {
      float cum = excl[p];
      float pos = (float)(irow - (p * 256 + c0));
#pragma unroll
      for (int j = 0; j < 4; ++j) {
        const int c = p * 256 + c0 + j;
        cum += e[p * 4 + j];
        const float tail = (Z - cum) * invZ;
        const float dist = sqrtf(fmaxf(tail * pos, 0.f));
        const float eff = fmaxf(__expf(g * dist), 1e-5f);
        const float x = (c <= irow) ? __expf(sv[p * 4 + j] * eff) : 0.f;
        e[p * 4 + j] = x;
        ls2 += x;
        pos -= 1.f;
      }
    }
    const float i2 = 1.f / wsum(ls2);

    float* grow = shead + (size_t)irow * Ssz;
#pragma unroll
    for (int p = 0; p < NP; ++p) {
      floatx4 o;
      o.x = e[p * 4 + 0] * i2; o.y = e[p * 4 + 1] * i2;
      o.z = e[p * 4 + 2] * i2; o.w = e[p * 4 + 3] * i2;
      __builtin_nontemporal_store(o, (floatx4*)(grow + p * 256 + c0));
      uint2 pk;
      pk.x = (uint)(unsigned short)f2bf(o.x) | ((uint)(unsigned short)f2bf(o.y) << 16);
      pk.y = (uint)(unsigned short)f2bf(o.z) | ((uint)(unsigned short)f2bf(o.w) << 16);
      *(uint2*)(srow + p * 256 + c0) = pk;
    }
  }
}

__global__ __launch_bounds__(256, 4) void attn_kernel(
    const short* __restrict__ qh, const short* __restrict__ kh,
    const short* __restrict__ vt, const float* __restrict__ gammas,
    float* __restrict__ scores_out, short* __restrict__ oc) {
  __shared__ short ss[16 * SST];

  const int tid = threadIdx.x, ln = tid & 63, w = tid >> 6;
  const int lm = ln & 15, qq = ln >> 4;
  const int bh = blockIdx.x >> 6;
  const int row0 = (63 - (blockIdx.x & 63)) << 4;  // heavy tiles first
  const int h = bh & 7, b = bh >> 3;
  const float scale = 0.17677669529663687f;
  const float g = -fabsf(gammas[h]);

  const short* qhead = qh + (size_t)bh * Ssz * DHn;
  const short* khead = kh + (size_t)bh * Ssz * DHn;
  const short* vhead = vt + (size_t)bh * DHn * Ssz;
  float* shead = scores_out + ((size_t)bh << 20);

  const short8 qa = *(const short8*)(qhead + (row0 + lm) * DHn + qq * 8);

  // phase 1: QK^T -> fp16 raw scores in LDS (causal tiles only)
  const int ntile = (row0 >> 4) + 1;
  for (int t = w; t < ntile; t += 4) {
    const int n0 = t * 16;
    const short8 kb = *(const short8*)(khead + (n0 + lm) * DHn + qq * 8);
    floatx4 c = {0.f, 0.f, 0.f, 0.f};
    c = __builtin_amdgcn_mfma_f32_16x16x32_bf16(qa, kb, c, 0, 0, 0);
#pragma unroll
    for (int r = 0; r < 4; ++r)
      ss[(qq * 4 + r) * SST + n0 + lm] = f2h(c[r] * scale);
  }
  __syncthreads();

  // phase 2
  const int NPc = (row0 >> 8) + 1;
  switch (NPc) {
    case 1: phase2<1>(ss, shead, row0, w, ln, g); break;
    case 2: phase2<2>(ss, shead, row0, w, ln, g); break;
    case 3: phase2<3>(ss, shead, row0, w, ln, g); break;
    default: phase2<4>(ss, shead, row0, w, ln, g); break;
  }

  // zero-fill masked tail of scores rows (non-temporal)
  if (NPc < 4) {
    const floatx4 z4 = {0.f, 0.f, 0.f, 0.f};
    for (int r = 0; r < 16; ++r) {
      float* grow = shead + (size_t)(row0 + r) * Ssz + NPc * 256;
      for (int i = tid; i < (4 - NPc) * 64; i += 256)
        __builtin_nontemporal_store(z4, ((floatx4*)grow) + i);
    }
  }
  __syncthreads();

  // phase 3: PV via MFMA
  floatx4 o0 = {0.f, 0.f, 0.f, 0.f}, o1 = {0.f, 0.f, 0.f, 0.f};
  const int nkt = (row0 >> 5) + 1;
  for (int kt = w; kt < nkt; kt += 4) {
    const int k0 = kt * 32;
    const short8 av = *(const short8*)(ss + lm * SST + k0 + qq * 8);
    const short8 b0 = *(const short8*)(vhead + (lm << 10) + k0 + qq * 8);
    const short8 b1 = *(const short8*)(vhead + ((16 + lm) << 10) + k0 + qq * 8);
    o0 = __builtin_amdgcn_mfma_f32_16x16x32_bf16(av, b0, o0, 0, 0, 0);
    o1 = __builtin_amdgcn_mfma_f32_16x16x32_bf16(av, b1, o1, 0, 0, 0);
  }
  __syncthreads();
  float* red = (float*)ss;  // alias, 8 KB
#pragma unroll
  for (int r = 0; r < 4; ++r) {
    red[(w * 16 + qq * 4 + r) * 32 + lm] = o0[r];
    red[(w * 16 + qq * 4 + r) * 32 + 16 + lm] = o1[r];
  }
  __syncthreads();
  {
    const int m = tid >> 4, n = tid & 15;
    float a0 = 0.f, a1 = 0.f;
#pragma unroll
    for (int wv = 0; wv < 4; ++wv) {
      a0 += red[(wv * 16 + m) * 32 + n];
      a1 += red[(wv * 16 + m) * 32 + 16 + n];
    }
    const size_t row = ((size_t)b << 10) + row0 + m;
    oc[row * Dsz + h * DHn + n] = f2bf(a0);
    oc[row * Dsz + h * DHn + 16 + n] = f2bf(a1);
  }
}

// ---------------- launch ---------------------------------------------------
extern "C" void kernel_launch(void* const* d_in, const int* in_sizes, int n_in,
                              void* d_out, int out_size, void* d_ws, size_t ws_size,
                              hipStream_t stream) {
  const float* q  = (const float*)d_in[0];
  const float* k  = (const float*)d_in[1];
  const float* v  = (const float*)d_in[2];
  const float* Wq = (const float*)d_in[4];
  const float* bq = (const float*)d_in[5];
  const float* Wv = (const float*)d_in[6];
  const float* bv = (const float*)d_in[7];
  const float* Wo = (const float*)d_in[8];
  const float* bo = (const float*)d_in[9];
  const float* gm = (const float*)d_in[10];

  float* out    = (float*)d_out;                  // [B,S,D] fp32
  float* scores = out + (size_t)Bsz * Ssz * Dsz;  // [B,H,S,S] fp32

  const size_t Q = (size_t)Bsz * Hn * Ssz * DHn;
  short* qh = (short*)d_ws;        // bf16 [B,H,S,DH]
  short* kh = qh + Q;
  short* vt = kh + Q;              // bf16 [B,H,DH,S]
  short* oc = vt + Q;              // bf16 [B,S,D]
  short* Wf = oc + Q;              // bf16 frag-order weights, 3 x 65536

  const dim3 blk(256);
  hipLaunchKernelGGL(cvt_wfrag, dim3(32, 3), blk, 0, stream, Wq, Wv, Wo, Wf);
  hipLaunchKernelGGL(proj_qkv2, dim3(256, 3), blk, 0, stream,
                     q, k, v, Wf, bq, bv, qh, kh, vt);
  hipLaunchKernelGGL(attn_kernel, dim3(Bsz * Hn * (Ssz / 16)), blk, 0, stream,
                     qh, kh, vt, gm, scores, oc);
  hipLaunchKernelGGL(proj_out2, dim3(256), blk, 0, stream, oc, Wf, bo, out);
}

// Round 2
// 361.992 us; speedup vs baseline: 1.0560x; 1.0106x over previous
//
#include <hip/hip_runtime.h>
#include <hip/hip_fp16.h>
#include <math.h>

// B=8, S=1024, D=256, H=8, DH=32
constexpr int Bsz = 8, Ssz = 1024, Dsz = 256, Hn = 8, DHn = 32;
constexpr int SST = 1160;  // attn LDS row stride in shorts

typedef __attribute__((ext_vector_type(8))) short short8;
typedef __attribute__((ext_vector_type(4))) float floatx4;

#define DEV static __device__ __forceinline__

DEV short f2bf(float f) {  // fp32 -> bf16 RNE
  union { float f; unsigned u; } x; x.f = f;
  return (short)((x.u + 0x7fffu + ((x.u >> 16) & 1u)) >> 16);
}
DEV short f2h(float f) {
  __half h = __float2half(f);
  return *(short*)&h;
}
DEV unsigned bfpk(float lo, float hi) {  // v_cvt_pk_bf16_f32: {hi,lo} -> 2xbf16
  unsigned r;
  asm("v_cvt_pk_bf16_f32 %0, %1, %2" : "=v"(r) : "v"(lo), "v"(hi));
  return r;
}
DEV float wsum(float v) {
#pragma unroll
  for (int off = 32; off > 0; off >>= 1) v += __shfl_xor(v, off, 64);
  return v;
}

// ============ W pre-convert: fp32 row-major -> bf16 MFMA B-frag order =======
// layout: [kblk(8)][ntile(16)][lane(64)][8 bf16]; element =
//   W[ntile*16 + (lane&15)][kblk*32 + (lane>>4)*8 + j]
__global__ __launch_bounds__(256) void cvt_wfrag(const float* __restrict__ Wq,
                                                 const float* __restrict__ Wv,
                                                 const float* __restrict__ Wo,
                                                 short* __restrict__ dst) {
  const int which = blockIdx.y;
  const float* W = (which == 0) ? Wq : (which == 1) ? Wv : Wo;
  const int t = blockIdx.x * 256 + threadIdx.x;  // 0..8191
  const int ln = t & 63, nt = (t >> 6) & 15, kblk = t >> 10;
  const float* src = W + (size_t)(nt * 16 + (ln & 15)) * 256 + kblk * 32 + (ln >> 4) * 8;
  const float4 a = *(const float4*)src;
  const float4 b = *(const float4*)(src + 4);
  const float tmp[8] = {a.x, a.y, a.z, a.w, b.x, b.y, b.z, b.w};
  short8 s;
#pragma unroll
  for (int j = 0; j < 8; ++j) s[j] = f2bf(tmp[j]);
  *(short8*)(dst + ((size_t)which << 16) + (size_t)t * 8) = s;
}

// ============ projections: 32 rows x full N=256 per block ==================
// Xs: 32x80 bf16, granule-XOR swizzled. Wave w owns n-range [w*64, w*64+64).
__global__ __launch_bounds__(256, 4) void proj_qkv2(
    const float* __restrict__ qi, const float* __restrict__ ki, const float* __restrict__ vi,
    const short* __restrict__ Wfrag, const float* __restrict__ bq, const float* __restrict__ bv,
    short* __restrict__ qh, short* __restrict__ kh, short* __restrict__ vt) {
  __shared__ short Xs[32 * 80];
  const int which = blockIdx.y;
  const float* X = (which == 0) ? qi : (which == 1) ? ki : vi;
  const short* Wf = Wfrag + ((which == 2) ? (1 << 16) : 0);
  const float* bias = (which == 2) ? bv : bq;
  const int tid = threadIdx.x, ln = tid & 63, w = tid >> 6;
  const int lm = ln & 15, qq = ln >> 4;
  const int bm = blockIdx.x;  // 256 blocks of 32 rows
  const float* Xb = X + (size_t)bm * 32 * 256;
  floatx4 acc[2][4] = {};

  for (int k0 = 0; k0 < 4; ++k0) {
    __syncthreads();
    {
      const int row = tid >> 3, cg = tid & 7;
#pragma unroll
      for (int i = 0; i < 2; ++i) {
        const float4 f = *(const float4*)(Xb + (size_t)row * 256 + k0 * 64 + cg * 8 + i * 4);
        short4 s; s.x = f2bf(f.x); s.y = f2bf(f.y); s.z = f2bf(f.z); s.w = f2bf(f.w);
        *(short4*)(Xs + row * 80 + (cg ^ (row & 7)) * 8 + i * 4) = s;
      }
    }
    __syncthreads();
#pragma unroll
    for (int ks = 0; ks < 2; ++ks) {
      const int kblk = k0 * 2 + ks;
      short8 a[2], b[4];
#pragma unroll
      for (int mt = 0; mt < 2; ++mt) {
        const int row = mt * 16 + lm;
        a[mt] = *(const short8*)(Xs + row * 80 + (((ks * 4 + qq)) ^ (row & 7)) * 8);
      }
#pragma unroll
      for (int nt = 0; nt < 4; ++nt)
        b[nt] = *(const short8*)(Wf + ((size_t)(kblk * 16 + w * 4 + nt) * 64 + ln) * 8);
#pragma unroll
      for (int mt = 0; mt < 2; ++mt)
#pragma unroll
        for (int nt = 0; nt < 4; ++nt)
          acc[mt][nt] = __builtin_amdgcn_mfma_f32_16x16x32_bf16(a[mt], b[nt], acc[mt][nt], 0, 0, 0);
    }
  }

#pragma unroll
  for (int mt = 0; mt < 2; ++mt) {
#pragma unroll
    for (int nt = 0; nt < 4; ++nt) {
      const int n = w * 64 + nt * 16 + lm;
      const float bval = bias[n];
      const int m0 = bm * 32 + mt * 16 + qq * 4;
      const int h = n >> 5, dh = n & 31;
      if (which <= 1) {  // head-split [B,H,S,DH]
        short* dst = (which == 0) ? qh : kh;
#pragma unroll
        for (int r = 0; r < 4; ++r) {
          const int m = m0 + r, b_ = m >> 10, s = m & 1023;
          dst[(((size_t)(b_ * Hn + h) << 10) + s) * DHn + dh] = f2bf(acc[mt][nt][r] + bval);
        }
      } else {  // V^T [B,H,DH,S]
        const int b_ = m0 >> 10, s0 = m0 & 1023;
        short4 pk;
        pk.x = f2bf(acc[mt][nt][0] + bval);
        pk.y = f2bf(acc[mt][nt][1] + bval);
        pk.z = f2bf(acc[mt][nt][2] + bval);
        pk.w = f2bf(acc[mt][nt][3] + bval);
        *(short4*)(vt + ((size_t)((b_ * Hn + h) * DHn + dh) << 10) + s0) = pk;
      }
    }
  }
}

__global__ __launch_bounds__(256, 4) void proj_out2(
    const short* __restrict__ oc, const short* __restrict__ Wfrag,
    const float* __restrict__ bo, float* __restrict__ out) {
  __shared__ short Xs[32 * 80];
  const short* Wf = Wfrag + (2 << 16);
  const int tid = threadIdx.x, ln = tid & 63, w = tid >> 6;
  const int lm = ln & 15, qq = ln >> 4;
  const int bm = blockIdx.x;
  const short* Xb = oc + (size_t)bm * 32 * 256;
  floatx4 acc[2][4] = {};

  for (int k0 = 0; k0 < 4; ++k0) {
    __syncthreads();
    {
      const int row = tid >> 3, cg = tid & 7;
      const short8 s = *(const short8*)(Xb + (size_t)row * 256 + k0 * 64 + cg * 8);
      *(short8*)(Xs + row * 80 + (cg ^ (row & 7)) * 8) = s;
    }
    __syncthreads();
#pragma unroll
    for (int ks = 0; ks < 2; ++ks) {
      const int kblk = k0 * 2 + ks;
      short8 a[2], b[4];
#pragma unroll
      for (int mt = 0; mt < 2; ++mt) {
        const int row = mt * 16 + lm;
        a[mt] = *(const short8*)(Xs + row * 80 + (((ks * 4 + qq)) ^ (row & 7)) * 8);
      }
#pragma unroll
      for (int nt = 0; nt < 4; ++nt)
        b[nt] = *(const short8*)(Wf + ((size_t)(kblk * 16 + w * 4 + nt) * 64 + ln) * 8);
#pragma unroll
      for (int mt = 0; mt < 2; ++mt)
#pragma unroll
        for (int nt = 0; nt < 4; ++nt)
          acc[mt][nt] = __builtin_amdgcn_mfma_f32_16x16x32_bf16(a[mt], b[nt], acc[mt][nt], 0, 0, 0);
    }
  }
#pragma unroll
  for (int mt = 0; mt < 2; ++mt)
#pragma unroll
    for (int nt = 0; nt < 4; ++nt) {
      const int n = w * 64 + nt * 16 + lm;
      const float bval = bo[n];
      const int m0 = bm * 32 + mt * 16 + qq * 4;
#pragma unroll
      for (int r = 0; r < 4; ++r)
        __builtin_nontemporal_store(acc[mt][nt][r] + bval, out + (size_t)(m0 + r) * 256 + n);
    }
}

// ======================= fused attention ===================================
// phase2 v3: latency-oriented restructure.
//  - All NP wave-scans advance in lockstep (independent chains, NP-wide ILP)
//    instead of the serial carry->scan->carry chain.
//  - Mask compare/select only on the diagonal chunk (p == NP-1); chunks
//    p < NP-1 are provably fully causal (p*256+255 <= row0 <= irow).
//  - P write-back packed with v_cvt_pk_bf16_f32 (1 instr / 2 elems) instead
//    of hand-rolled 3-op RNE per element.
template <int NP>
DEV void phase2(short* ss, float* shead, int row0, int w, int ln, float g) {
  const int c0 = ln * 4;
  for (int rr = 0; rr < 4; ++rr) {
    const int m = w * 4 + rr;
    const int irow = row0 + m;
    short* srow = ss + m * SST;

    float sv[NP * 4], e[NP * 4], ls[NP];

    // pass A: load raw fp16 scores, e = exp(s), per-lane chunk sums.
    // (exp with no max-subtraction is safe: |s| small, identical after norm.)
#pragma unroll
    for (int p = 0; p < NP; ++p) {
      const uint2 u = *(const uint2*)(srow + p * 256 + c0);
      const float2 f0 = __half22float2(*(const __half2*)&u.x);
      const float2 f1 = __half22float2(*(const __half2*)&u.y);
      sv[p * 4 + 0] = f0.x; sv[p * 4 + 1] = f0.y;
      sv[p * 4 + 2] = f1.x; sv[p * 4 + 3] = f1.y;
      float l = 0.f;
#pragma unroll
      for (int j = 0; j < 4; ++j) {
        float ex = __expf(sv[p * 4 + j]);
        if (p == NP - 1)  // only diagonal chunk can be masked
          ex = (p * 256 + c0 + j <= irow) ? ex : 0.f;
        e[p * 4 + j] = ex;
        l += ex;
      }
      ls[p] = l;
    }

    // NP independent wave-scans in lockstep, then cheap serial prefix of
    // chunk totals (removes the long carry->scan serialization).
    float incl[NP];
#pragma unroll
    for (int p = 0; p < NP; ++p) incl[p] = ls[p];
#pragma unroll
    for (int off = 1; off < 64; off <<= 1) {
#pragma unroll
      for (int p = 0; p < NP; ++p) {
        const float y = __shfl_up(incl[p], off, 64);
        if (ln >= off) incl[p] += y;
      }
    }
    float excl[NP], Z = 0.f;
#pragma unroll
    for (int p = 0; p < NP; ++p) {
      excl[p] = Z + incl[p] - ls[p];
      Z += __shfl(incl[p], 63, 64);
    }
    const float invZ = 1.f / Z;

    // pass B: distance decay + second (unnormalized) softmax numerator.
    // eff = exp(g*dist) <= 1 since g <= 0; lower clip 1e-5 can bind.
    float ls2 = 0.f;
#pragma unroll
    for (int p = 0; p < NP; ++p) {
      float cum = excl[p];
      float pos = (float)(irow - (p * 256 + c0));
#pragma unroll
      for (int j = 0; j < 4; ++j) {
        cum += e[p * 4 + j];
        const float tail = 1.f - cum * invZ;  // == (Z-cum)/Z
        const float dist = sqrtf(fmaxf(tail * pos, 0.f));
        const float eff = fmaxf(__expf(g * dist), 1e-5f);
        float x = __expf(sv[p * 4 + j] * eff);
        if (p == NP - 1)
          x = (p * 256 + c0 + j <= irow) ? x : 0.f;
        e[p * 4 + j] = x;
        ls2 += x;
        pos -= 1.f;
      }
    }
    const float i2 = 1.f / wsum(ls2);

    float* grow = shead + (size_t)irow * Ssz;
#pragma unroll
    for (int p = 0; p < NP; ++p) {
      floatx4 o;
      o.x = e[p * 4 + 0] * i2; o.y = e[p * 4 + 1] * i2;
      o.z = e[p * 4 + 2] * i2; o.w = e[p * 4 + 3] * i2;
      __builtin_nontemporal_store(o, (floatx4*)(grow + p * 256 + c0));
      uint2 pk;
      pk.x = bfpk(o.x, o.y);
      pk.y = bfpk(o.z, o.w);
      *(uint2*)(srow + p * 256 + c0) = pk;
    }
  }
}

__global__ __launch_bounds__(256, 4) void attn_kernel(
    const short* __restrict__ qh, const short* __restrict__ kh,
    const short* __restrict__ vt, const float* __restrict__ gammas,
    float* __restrict__ scores_out, short* __restrict__ oc) {
  __shared__ short ss[16 * SST];

  const int tid = threadIdx.x, ln = tid & 63, w = tid >> 6;
  const int lm = ln & 15, qq = ln >> 4;
  const int bh = blockIdx.x >> 6;
  const int row0 = (63 - (blockIdx.x & 63)) << 4;  // heavy tiles first
  const int h = bh & 7, b = bh >> 3;
  const float scale = 0.17677669529663687f;
  const float g = -fabsf(gammas[h]);

  const short* qhead = qh + (size_t)bh * Ssz * DHn;
  const short* khead = kh + (size_t)bh * Ssz * DHn;
  const short* vhead = vt + (size_t)bh * DHn * Ssz;
  float* shead = scores_out + ((size_t)bh << 20);

  const short8 qa = *(const short8*)(qhead + (row0 + lm) * DHn + qq * 8);

  // phase 1: QK^T -> fp16 raw scores in LDS (causal tiles only)
  const int ntile = (row0 >> 4) + 1;
  for (int t = w; t < ntile; t += 4) {
    const int n0 = t * 16;
    const short8 kb = *(const short8*)(khead + (n0 + lm) * DHn + qq * 8);
    floatx4 c = {0.f, 0.f, 0.f, 0.f};
    c = __builtin_amdgcn_mfma_f32_16x16x32_bf16(qa, kb, c, 0, 0, 0);
#pragma unroll
    for (int r = 0; r < 4; ++r)
      ss[(qq * 4 + r) * SST + n0 + lm] = f2h(c[r] * scale);
  }
  __syncthreads();

  // phase 2
  const int NPc = (row0 >> 8) + 1;
  switch (NPc) {
    case 1: phase2<1>(ss, shead, row0, w, ln, g); break;
    case 2: phase2<2>(ss, shead, row0, w, ln, g); break;
    case 3: phase2<3>(ss, shead, row0, w, ln, g); break;
    default: phase2<4>(ss, shead, row0, w, ln, g); break;
  }

  // zero-fill masked tail of scores rows (non-temporal)
  if (NPc < 4) {
    const floatx4 z4 = {0.f, 0.f, 0.f, 0.f};
    for (int r = 0; r < 16; ++r) {
      float* grow = shead + (size_t)(row0 + r) * Ssz + NPc * 256;
      for (int i = tid; i < (4 - NPc) * 64; i += 256)
        __builtin_nontemporal_store(z4, ((floatx4*)grow) + i);
    }
  }
  __syncthreads();

  // phase 3: PV via MFMA
  floatx4 o0 = {0.f, 0.f, 0.f, 0.f}, o1 = {0.f, 0.f, 0.f, 0.f};
  const int nkt = (row0 >> 5) + 1;
  for (int kt = w; kt < nkt; kt += 4) {
    const int k0 = kt * 32;
    const short8 av = *(const short8*)(ss + lm * SST + k0 + qq * 8);
    const short8 b0 = *(const short8*)(vhead + (lm << 10) + k0 + qq * 8);
    const short8 b1 = *(const short8*)(vhead + ((16 + lm) << 10) + k0 + qq * 8);
    o0 = __builtin_amdgcn_mfma_f32_16x16x32_bf16(av, b0, o0, 0, 0, 0);
    o1 = __builtin_amdgcn_mfma_f32_16x16x32_bf16(av, b1, o1, 0, 0, 0);
  }
  __syncthreads();
  float* red = (float*)ss;  // alias, 8 KB
#pragma unroll
  for (int r = 0; r < 4; ++r) {
    red[(w * 16 + qq * 4 + r) * 32 + lm] = o0[r];
    red[(w * 16 + qq * 4 + r) * 32 + 16 + lm] = o1[r];
  }
  __syncthreads();
  {
    const int m = tid >> 4, n = tid & 15;
    float a0 = 0.f, a1 = 0.f;
#pragma unroll
    for (int wv = 0; wv < 4; ++wv) {
      a0 += red[(wv * 16 + m) * 32 + n];
      a1 += red[(wv * 16 + m) * 32 + 16 + n];
    }
    const size_t row = ((size_t)b << 10) + row0 + m;
    oc[row * Dsz + h * DHn + n] = f2bf(a0);
    oc[row * Dsz + h * DHn + 16 + n] = f2bf(a1);
  }
}

// ---------------- launch ---------------------------------------------------
extern "C" void kernel_launch(void* const* d_in, const int* in_sizes, int n_in,
                              void* d_out, int out_size, void* d_ws, size_t ws_size,
                              hipStream_t stream) {
  const float* q  = (const float*)d_in[0];
  const float* k  = (const float*)d_in[1];
  const float* v  = (const float*)d_in[2];
  const float* Wq = (const float*)d_in[4];
  const float* bq = (const float*)d_in[5];
  const float* Wv = (const float*)d_in[6];
  const float* bv = (const float*)d_in[7];
  const float* Wo = (const float*)d_in[8];
  const float* bo = (const float*)d_in[9];
  const float* gm = (const float*)d_in[10];

  float* out    = (float*)d_out;                  // [B,S,D] fp32
  float* scores = out + (size_t)Bsz * Ssz * Dsz;  // [B,H,S,S] fp32

  const size_t Q = (size_t)Bsz * Hn * Ssz * DHn;
  short* qh = (short*)d_ws;        // bf16 [B,H,S,DH]
  short* kh = qh + Q;
  short* vt = kh + Q;              // bf16 [B,H,DH,S]
  short* oc = vt + Q;              // bf16 [B,S,D]
  short* Wf = oc + Q;              // bf16 frag-order weights, 3 x 65536

  const dim3 blk(256);
  hipLaunchKernelGGL(cvt_wfrag, dim3(32, 3), blk, 0, stream, Wq, Wv, Wo, Wf);
  hipLaunchKernelGGL(proj_qkv2, dim3(256, 3), blk, 0, stream,
                     q, k, v, Wf, bq, bv, qh, kh, vt);
  hipLaunchKernelGGL(attn_kernel, dim3(Bsz * Hn * (Ssz / 16)), blk, 0, stream,
                     qh, kh, vt, gm, scores, oc);
  hipLaunchKernelGGL(proj_out2, dim3(256), blk, 0, stream, oc, Wf, bo, out);
}

// Round 3
// 356.444 us; speedup vs baseline: 1.0725x; 1.0156x over previous
//
#include <hip/hip_runtime.h>
#include <hip/hip_fp16.h>
#include <math.h>

// B=8, S=1024, D=256, H=8, DH=32
constexpr int Bsz = 8, Ssz = 1024, Dsz = 256, Hn = 8, DHn = 32;
constexpr int SST = 1160;  // attn LDS row stride in shorts

typedef __attribute__((ext_vector_type(8))) short short8;
typedef __attribute__((ext_vector_type(4))) float floatx4;

#define DEV static __device__ __forceinline__

DEV short f2bf(float f) {  // fp32 -> bf16 RNE
  union { float f; unsigned u; } x; x.f = f;
  return (short)((x.u + 0x7fffu + ((x.u >> 16) & 1u)) >> 16);
}
DEV short f2h(float f) {
  __half h = __float2half(f);
  return *(short*)&h;
}
DEV unsigned bfpk(float lo, float hi) {  // v_cvt_pk_bf16_f32: {hi,lo} -> 2xbf16
  unsigned r;
  asm("v_cvt_pk_bf16_f32 %0, %1, %2" : "=v"(r) : "v"(lo), "v"(hi));
  return r;
}
DEV float ex2(float x) {  // raw v_exp_f32 (2^x)
#if __has_builtin(__builtin_amdgcn_exp2f)
  return __builtin_amdgcn_exp2f(x);
#else
  return __expf(x * 0.69314718055994531f);
#endif
}
DEV float wsum(float v) {
#pragma unroll
  for (int off = 32; off > 0; off >>= 1) v += __shfl_xor(v, off, 64);
  return v;
}

// ============ W pre-convert: fp32 row-major -> bf16 MFMA B-frag order =======
// layout: [kblk(8)][ntile(16)][lane(64)][8 bf16]; element =
//   W[ntile*16 + (lane&15)][kblk*32 + (lane>>4)*8 + j]
__global__ __launch_bounds__(256) void cvt_wfrag(const float* __restrict__ Wq,
                                                 const float* __restrict__ Wv,
                                                 const float* __restrict__ Wo,
                                                 short* __restrict__ dst) {
  const int which = blockIdx.y;
  const float* W = (which == 0) ? Wq : (which == 1) ? Wv : Wo;
  const int t = blockIdx.x * 256 + threadIdx.x;  // 0..8191
  const int ln = t & 63, nt = (t >> 6) & 15, kblk = t >> 10;
  const float* src = W + (size_t)(nt * 16 + (ln & 15)) * 256 + kblk * 32 + (ln >> 4) * 8;
  const float4 a = *(const float4*)src;
  const float4 b = *(const float4*)(src + 4);
  const float tmp[8] = {a.x, a.y, a.z, a.w, b.x, b.y, b.z, b.w};
  short8 s;
#pragma unroll
  for (int j = 0; j < 8; ++j) s[j] = f2bf(tmp[j]);
  *(short8*)(dst + ((size_t)which << 16) + (size_t)t * 8) = s;
}

// ============ projections: 32 rows x full N=256 per block ==================
// Xs: 32x80 bf16, granule-XOR swizzled. Wave w owns n-range [w*64, w*64+64).
__global__ __launch_bounds__(256, 4) void proj_qkv2(
    const float* __restrict__ qi, const float* __restrict__ ki, const float* __restrict__ vi,
    const short* __restrict__ Wfrag, const float* __restrict__ bq, const float* __restrict__ bv,
    short* __restrict__ qh, short* __restrict__ kh, short* __restrict__ vt) {
  __shared__ short Xs[32 * 80];
  const int which = blockIdx.y;
  const float* X = (which == 0) ? qi : (which == 1) ? ki : vi;
  const short* Wf = Wfrag + ((which == 2) ? (1 << 16) : 0);
  const float* bias = (which == 2) ? bv : bq;
  const int tid = threadIdx.x, ln = tid & 63, w = tid >> 6;
  const int lm = ln & 15, qq = ln >> 4;
  const int bm = blockIdx.x;  // 256 blocks of 32 rows
  const float* Xb = X + (size_t)bm * 32 * 256;
  floatx4 acc[2][4] = {};

  for (int k0 = 0; k0 < 4; ++k0) {
    __syncthreads();
    {
      const int row = tid >> 3, cg = tid & 7;
#pragma unroll
      for (int i = 0; i < 2; ++i) {
        const float4 f = *(const float4*)(Xb + (size_t)row * 256 + k0 * 64 + cg * 8 + i * 4);
        short4 s; s.x = f2bf(f.x); s.y = f2bf(f.y); s.z = f2bf(f.z); s.w = f2bf(f.w);
        *(short4*)(Xs + row * 80 + (cg ^ (row & 7)) * 8 + i * 4) = s;
      }
    }
    __syncthreads();
#pragma unroll
    for (int ks = 0; ks < 2; ++ks) {
      const int kblk = k0 * 2 + ks;
      short8 a[2], b[4];
#pragma unroll
      for (int mt = 0; mt < 2; ++mt) {
        const int row = mt * 16 + lm;
        a[mt] = *(const short8*)(Xs + row * 80 + (((ks * 4 + qq)) ^ (row & 7)) * 8);
      }
#pragma unroll
      for (int nt = 0; nt < 4; ++nt)
        b[nt] = *(const short8*)(Wf + ((size_t)(kblk * 16 + w * 4 + nt) * 64 + ln) * 8);
#pragma unroll
      for (int mt = 0; mt < 2; ++mt)
#pragma unroll
        for (int nt = 0; nt < 4; ++nt)
          acc[mt][nt] = __builtin_amdgcn_mfma_f32_16x16x32_bf16(a[mt], b[nt], acc[mt][nt], 0, 0, 0);
    }
  }

#pragma unroll
  for (int mt = 0; mt < 2; ++mt) {
#pragma unroll
    for (int nt = 0; nt < 4; ++nt) {
      const int n = w * 64 + nt * 16 + lm;
      const float bval = bias[n];
      const int m0 = bm * 32 + mt * 16 + qq * 4;
      const int h = n >> 5, dh = n & 31;
      if (which <= 1) {  // head-split [B,H,S,DH]
        short* dst = (which == 0) ? qh : kh;
#pragma unroll
        for (int r = 0; r < 4; ++r) {
          const int m = m0 + r, b_ = m >> 10, s = m & 1023;
          dst[(((size_t)(b_ * Hn + h) << 10) + s) * DHn + dh] = f2bf(acc[mt][nt][r] + bval);
        }
      } else {  // V^T [B,H,DH,S]
        const int b_ = m0 >> 10, s0 = m0 & 1023;
        short4 pk;
        pk.x = f2bf(acc[mt][nt][0] + bval);
        pk.y = f2bf(acc[mt][nt][1] + bval);
        pk.z = f2bf(acc[mt][nt][2] + bval);
        pk.w = f2bf(acc[mt][nt][3] + bval);
        *(short4*)(vt + ((size_t)((b_ * Hn + h) * DHn + dh) << 10) + s0) = pk;
      }
    }
  }
}

__global__ __launch_bounds__(256, 4) void proj_out2(
    const short* __restrict__ oc, const short* __restrict__ Wfrag,
    const float* __restrict__ bo, float* __restrict__ out) {
  __shared__ short Xs[32 * 80];
  const short* Wf = Wfrag + (2 << 16);
  const int tid = threadIdx.x, ln = tid & 63, w = tid >> 6;
  const int lm = ln & 15, qq = ln >> 4;
  const int bm = blockIdx.x;
  const short* Xb = oc + (size_t)bm * 32 * 256;
  floatx4 acc[2][4] = {};

  for (int k0 = 0; k0 < 4; ++k0) {
    __syncthreads();
    {
      const int row = tid >> 3, cg = tid & 7;
      const short8 s = *(const short8*)(Xb + (size_t)row * 256 + k0 * 64 + cg * 8);
      *(short8*)(Xs + row * 80 + (cg ^ (row & 7)) * 8) = s;
    }
    __syncthreads();
#pragma unroll
    for (int ks = 0; ks < 2; ++ks) {
      const int kblk = k0 * 2 + ks;
      short8 a[2], b[4];
#pragma unroll
      for (int mt = 0; mt < 2; ++mt) {
        const int row = mt * 16 + lm;
        a[mt] = *(const short8*)(Xs + row * 80 + (((ks * 4 + qq)) ^ (row & 7)) * 8);
      }
#pragma unroll
      for (int nt = 0; nt < 4; ++nt)
        b[nt] = *(const short8*)(Wf + ((size_t)(kblk * 16 + w * 4 + nt) * 64 + ln) * 8);
#pragma unroll
      for (int mt = 0; mt < 2; ++mt)
#pragma unroll
        for (int nt = 0; nt < 4; ++nt)
          acc[mt][nt] = __builtin_amdgcn_mfma_f32_16x16x32_bf16(a[mt], b[nt], acc[mt][nt], 0, 0, 0);
    }
  }
#pragma unroll
  for (int mt = 0; mt < 2; ++mt)
#pragma unroll
    for (int nt = 0; nt < 4; ++nt) {
      const int n = w * 64 + nt * 16 + lm;
      const float bval = bo[n];
      const int m0 = bm * 32 + mt * 16 + qq * 4;
#pragma unroll
      for (int r = 0; r < 4; ++r)
        __builtin_nontemporal_store(acc[mt][nt][r] + bval, out + (size_t)(m0 + r) * 256 + n);
    }
}

// ======================= fused attention ===================================
// phase2 v4: pure issue-slot reduction (R0 calibration: ~2.7us per slot/elem).
//  - LDS holds t = score * log2(e) (pre-scaled in phase 1): both exps become
//    raw v_exp_f32 (exp2), no per-element ln2 muls.
//  - eff = exp2(g2*dist), g2 = g*log2e hoisted.
//  - fmax(t,0) before sqrt replaced by free |.| input modifier (valid: causal
//    tail >= -2eps; masked-lane junk is cndmask'd to 0 afterward).
template <int NP>
DEV void phase2(short* ss, float* shead, int row0, int w, int ln, float g2) {
  const int c0 = ln * 4;
  for (int rr = 0; rr < 4; ++rr) {
    const int m = w * 4 + rr;
    const int irow = row0 + m;
    short* srow = ss + m * SST;

    float sv[NP * 4], e[NP * 4], ls[NP];

    // pass A: load t (= score*log2e) from fp16 LDS, e = 2^t, chunk sums.
#pragma unroll
    for (int p = 0; p < NP; ++p) {
      const uint2 u = *(const uint2*)(srow + p * 256 + c0);
      const float2 f0 = __half22float2(*(const __half2*)&u.x);
      const float2 f1 = __half22float2(*(const __half2*)&u.y);
      sv[p * 4 + 0] = f0.x; sv[p * 4 + 1] = f0.y;
      sv[p * 4 + 2] = f1.x; sv[p * 4 + 3] = f1.y;
      float l = 0.f;
#pragma unroll
      for (int j = 0; j < 4; ++j) {
        float ex = ex2(sv[p * 4 + j]);
        if (p == NP - 1)  // only diagonal chunk can be masked
          ex = (p * 256 + c0 + j <= irow) ? ex : 0.f;
        e[p * 4 + j] = ex;
        l += ex;
      }
      ls[p] = l;
    }

    // NP independent wave-scans in lockstep, then serial prefix of totals.
    float incl[NP];
#pragma unroll
    for (int p = 0; p < NP; ++p) incl[p] = ls[p];
#pragma unroll
    for (int off = 1; off < 64; off <<= 1) {
#pragma unroll
      for (int p = 0; p < NP; ++p) {
        const float y = __shfl_up(incl[p], off, 64);
        if (ln >= off) incl[p] += y;
      }
    }
    float excl[NP], Z = 0.f;
#pragma unroll
    for (int p = 0; p < NP; ++p) {
      excl[p] = Z + incl[p] - ls[p];
      Z += __shfl(incl[p], 63, 64);
    }
    const float invZ = 1.f / Z;

    // pass B: distance decay + second (unnormalized) softmax numerator.
    float ls2 = 0.f;
#pragma unroll
    for (int p = 0; p < NP; ++p) {
      float cum = excl[p];
      float pos = (float)(irow - (p * 256 + c0));
#pragma unroll
      for (int j = 0; j < 4; ++j) {
        cum += e[p * 4 + j];
        const float tail = 1.f - cum * invZ;  // == (Z-cum)/Z
        const float dist = sqrtf(__builtin_fabsf(tail * pos));
        const float eff = fmaxf(ex2(g2 * dist), 1e-5f);
        float x = ex2(sv[p * 4 + j] * eff);
        if (p == NP - 1)
          x = (p * 256 + c0 + j <= irow) ? x : 0.f;
        e[p * 4 + j] = x;
        ls2 += x;
        pos -= 1.f;
      }
    }
    const float i2 = 1.f / wsum(ls2);

    float* grow = shead + (size_t)irow * Ssz;
#pragma unroll
    for (int p = 0; p < NP; ++p) {
      floatx4 o;
      o.x = e[p * 4 + 0] * i2; o.y = e[p * 4 + 1] * i2;
      o.z = e[p * 4 + 2] * i2; o.w = e[p * 4 + 3] * i2;
      __builtin_nontemporal_store(o, (floatx4*)(grow + p * 256 + c0));
      uint2 pk;
      pk.x = bfpk(o.x, o.y);
      pk.y = bfpk(o.z, o.w);
      *(uint2*)(srow + p * 256 + c0) = pk;
    }
  }
}

__global__ __launch_bounds__(256, 4) void attn_kernel(
    const short* __restrict__ qh, const short* __restrict__ kh,
    const short* __restrict__ vt, const float* __restrict__ gammas,
    float* __restrict__ scores_out, short* __restrict__ oc) {
  __shared__ short ss[16 * SST];

  const int tid = threadIdx.x, ln = tid & 63, w = tid >> 6;
  const int lm = ln & 15, qq = ln >> 4;
  const int bh = blockIdx.x >> 6;
  const int row0 = (63 - (blockIdx.x & 63)) << 4;  // heavy tiles first
  const int h = bh & 7, b = bh >> 3;
  // scale * log2(e): LDS scores hold t = s*log2e so exps are raw v_exp_f32
  const float scaleL2e = 0.17677669529663687f * 1.4426950408889634f;
  const float g2 = -fabsf(gammas[h]) * 1.4426950408889634f;

  const short* qhead = qh + (size_t)bh * Ssz * DHn;
  const short* khead = kh + (size_t)bh * Ssz * DHn;
  const short* vhead = vt + (size_t)bh * DHn * Ssz;
  float* shead = scores_out + ((size_t)bh << 20);

  const short8 qa = *(const short8*)(qhead + (row0 + lm) * DHn + qq * 8);

  // phase 1: QK^T -> fp16 t-values in LDS (causal tiles only)
  const int ntile = (row0 >> 4) + 1;
  for (int t = w; t < ntile; t += 4) {
    const int n0 = t * 16;
    const short8 kb = *(const short8*)(khead + (n0 + lm) * DHn + qq * 8);
    floatx4 c = {0.f, 0.f, 0.f, 0.f};
    c = __builtin_amdgcn_mfma_f32_16x16x32_bf16(qa, kb, c, 0, 0, 0);
#pragma unroll
    for (int r = 0; r < 4; ++r)
      ss[(qq * 4 + r) * SST + n0 + lm] = f2h(c[r] * scaleL2e);
  }
  __syncthreads();

  // phase 2
  const int NPc = (row0 >> 8) + 1;
  switch (NPc) {
    case 1: phase2<1>(ss, shead, row0, w, ln, g2); break;
    case 2: phase2<2>(ss, shead, row0, w, ln, g2); break;
    case 3: phase2<3>(ss, shead, row0, w, ln, g2); break;
    default: phase2<4>(ss, shead, row0, w, ln, g2); break;
  }

  // zero-fill masked tail of scores rows (non-temporal)
  if (NPc < 4) {
    const floatx4 z4 = {0.f, 0.f, 0.f, 0.f};
    for (int r = 0; r < 16; ++r) {
      float* grow = shead + (size_t)(row0 + r) * Ssz + NPc * 256;
      for (int i = tid; i < (4 - NPc) * 64; i += 256)
        __builtin_nontemporal_store(z4, ((floatx4*)grow) + i);
    }
  }
  __syncthreads();

  // phase 3: PV via MFMA
  floatx4 o0 = {0.f, 0.f, 0.f, 0.f}, o1 = {0.f, 0.f, 0.f, 0.f};
  const int nkt = (row0 >> 5) + 1;
  for (int kt = w; kt < nkt; kt += 4) {
    const int k0 = kt * 32;
    const short8 av = *(const short8*)(ss + lm * SST + k0 + qq * 8);
    const short8 b0 = *(const short8*)(vhead + (lm << 10) + k0 + qq * 8);
    const short8 b1 = *(const short8*)(vhead + ((16 + lm) << 10) + k0 + qq * 8);
    o0 = __builtin_amdgcn_mfma_f32_16x16x32_bf16(av, b0, o0, 0, 0, 0);
    o1 = __builtin_amdgcn_mfma_f32_16x16x32_bf16(av, b1, o1, 0, 0, 0);
  }
  __syncthreads();
  float* red = (float*)ss;  // alias, 8 KB
#pragma unroll
  for (int r = 0; r < 4; ++r) {
    red[(w * 16 + qq * 4 + r) * 32 + lm] = o0[r];
    red[(w * 16 + qq * 4 + r) * 32 + 16 + lm] = o1[r];
  }
  __syncthreads();
  {
    const int m = tid >> 4, n = tid & 15;
    float a0 = 0.f, a1 = 0.f;
#pragma unroll
    for (int wv = 0; wv < 4; ++wv) {
      a0 += red[(wv * 16 + m) * 32 + n];
      a1 += red[(wv * 16 + m) * 32 + 16 + n];
    }
    const size_t row = ((size_t)b << 10) + row0 + m;
    oc[row * Dsz + h * DHn + n] = f2bf(a0);
    oc[row * Dsz + h * DHn + 16 + n] = f2bf(a1);
  }
}

// ---------------- launch ---------------------------------------------------
extern "C" void kernel_launch(void* const* d_in, const int* in_sizes, int n_in,
                              void* d_out, int out_size, void* d_ws, size_t ws_size,
                              hipStream_t stream) {
  const float* q  = (const float*)d_in[0];
  const float* k  = (const float*)d_in[1];
  const float* v  = (const float*)d_in[2];
  const float* Wq = (const float*)d_in[4];
  const float* bq = (const float*)d_in[5];
  const float* Wv = (const float*)d_in[6];
  const float* bv = (const float*)d_in[7];
  const float* Wo = (const float*)d_in[8];
  const float* bo = (const float*)d_in[9];
  const float* gm = (const float*)d_in[10];

  float* out    = (float*)d_out;                  // [B,S,D] fp32
  float* scores = out + (size_t)Bsz * Ssz * Dsz;  // [B,H,S,S] fp32

  const size_t Q = (size_t)Bsz * Hn * Ssz * DHn;
  short* qh = (short*)d_ws;        // bf16 [B,H,S,DH]
  short* kh = qh + Q;
  short* vt = kh + Q;              // bf16 [B,H,DH,S]
  short* oc = vt + Q;              // bf16 [B,S,D]
  short* Wf = oc + Q;              // bf16 frag-order weights, 3 x 65536

  const dim3 blk(256);
  hipLaunchKernelGGL(cvt_wfrag, dim3(32, 3), blk, 0, stream, Wq, Wv, Wo, Wf);
  hipLaunchKernelGGL(proj_qkv2, dim3(256, 3), blk, 0, stream,
                     q, k, v, Wf, bq, bv, qh, kh, vt);
  hipLaunchKernelGGL(attn_kernel, dim3(Bsz * Hn * (Ssz / 16)), blk, 0, stream,
                     qh, kh, vt, gm, scores, oc);
  hipLaunchKernelGGL(proj_out2, dim3(256), blk, 0, stream, oc, Wf, bo, out);
}